// Round 2
// baseline (12425.291 us; speedup 1.0000x reference)
//
#include <hip/hip_runtime.h>

#define BB 8
#define TT 512
#define DD 1024
#define HH 16
#define DKK 64
#define SS 1023

typedef unsigned short ushort_t;

__device__ __forceinline__ float us2f(unsigned short u) {
    unsigned int x = ((unsigned int)u) << 16;
    return __uint_as_float(x);
}
__device__ __forceinline__ unsigned short f2us(float f) {
    unsigned int x = __float_as_uint(f);
    unsigned int lsb = (x >> 16) & 1u;
    x += 0x7fffu + lsb;
    return (unsigned short)(x >> 16);
}

// flags[0] = 1 if float buffers are bf16, 0 if f32
// flags[1] = 1 if mask is int32, 0 if int8/bool
__global__ void detect_kernel(const unsigned short* __restrict__ w,
                              const unsigned int* __restrict__ mask,
                              int* __restrict__ flags) {
    if (threadIdx.x == 0 && blockIdx.x == 0) {
        int plaus = 0;
        for (int i = 0; i < 256; i++) {
            unsigned short hw = w[i];
            int e = (hw >> 7) & 0xFF;
            if (e == 0 || (e >= 87 && e <= 131)) plaus++;
        }
        flags[0] = (plaus >= 205) ? 1 : 0;
        int ok = 1;
        for (int i = 0; i < 64; i++) if (mask[i] > 1u) ok = 0;
        flags[1] = ok;
    }
}

// C[i,n] = sum_k A[i,k] * W[n,k] (+ bias[n])
// AMODE: 0 = A external (dtype per flag), 2 = A is ctx f32 in head-major ws layout
// OMODE: 0 = qkv scatter (q->f32 ws, k/v->bf16 ws), 1 = pos scatter bf16 ws,
//        2 = output [M,N] (dtype per flag)
template<int AMODE, int OMODE>
__global__ __launch_bounds__(256) void gemm_kernel(
    const void* __restrict__ Av, const void* __restrict__ Wv,
    const void* __restrict__ bias, const int* __restrict__ flags,
    float* __restrict__ qT, unsigned short* __restrict__ kB,
    unsigned short* __restrict__ vB, unsigned short* __restrict__ pB,
    void* __restrict__ oout, int M, int N, int K)
{
    const bool isbf = (flags[0] != 0);
    __shared__ float As[16][64];
    __shared__ float Bs[16][64];
    const int tid = threadIdx.x;
    const int tx = tid & 15, ty = tid >> 4;
    const int bn = blockIdx.x * 64, bm = blockIdx.y * 64;
    const int lm = tid >> 2;          // 0..63
    const int lk = (tid & 3) * 4;     // 0,4,8,12
    float acc[4][4] = {};

    for (int bk = 0; bk < K; bk += 16) {
        float a[4];
        const int gr = bm + lm;
        const bool arow_ok = (OMODE != 1) || (gr < M);
        if (arow_ok) {
            if (AMODE == 0) {
                if (isbf) {
                    const unsigned short* ap = (const unsigned short*)Av + (size_t)gr * K + bk + lk;
                    ushort4 u = *(const ushort4*)ap;
                    a[0] = us2f(u.x); a[1] = us2f(u.y); a[2] = us2f(u.z); a[3] = us2f(u.w);
                } else {
                    const float* ap = (const float*)Av + (size_t)gr * K + bk + lk;
                    float4 u = *(const float4*)ap;
                    a[0] = u.x; a[1] = u.y; a[2] = u.z; a[3] = u.w;
                }
            } else {
                // ctx f32, head-major: A[i][k] = qT[(((i>>9)*16 + (k>>6))*512 + (i&511))*64 + (k&63)]
                const int kk0 = bk + lk;
                const float* ap = qT + (((size_t)(((gr >> 9) * HH) + (kk0 >> 6)) * TT + (gr & 511)) << 6) + (kk0 & 63);
                float4 u = *(const float4*)ap;
                a[0] = u.x; a[1] = u.y; a[2] = u.z; a[3] = u.w;
            }
        } else {
            a[0] = a[1] = a[2] = a[3] = 0.0f;
        }
        float bw[4];
        if (isbf) {
            const unsigned short* wp = (const unsigned short*)Wv + (size_t)(bn + lm) * K + bk + lk;
            ushort4 wu = *(const ushort4*)wp;
            bw[0] = us2f(wu.x); bw[1] = us2f(wu.y); bw[2] = us2f(wu.z); bw[3] = us2f(wu.w);
        } else {
            const float* wp = (const float*)Wv + (size_t)(bn + lm) * K + bk + lk;
            float4 wu = *(const float4*)wp;
            bw[0] = wu.x; bw[1] = wu.y; bw[2] = wu.z; bw[3] = wu.w;
        }

        __syncthreads();
        As[lk + 0][lm] = a[0]; As[lk + 1][lm] = a[1];
        As[lk + 2][lm] = a[2]; As[lk + 3][lm] = a[3];
        Bs[lk + 0][lm] = bw[0]; Bs[lk + 1][lm] = bw[1];
        Bs[lk + 2][lm] = bw[2]; Bs[lk + 3][lm] = bw[3];
        __syncthreads();

        #pragma unroll
        for (int kk = 0; kk < 16; kk++) {
            float4 av = *(const float4*)&As[kk][ty * 4];
            float4 bv = *(const float4*)&Bs[kk][tx * 4];
            float ar[4] = {av.x, av.y, av.z, av.w};
            float br[4] = {bv.x, bv.y, bv.z, bv.w};
            #pragma unroll
            for (int r = 0; r < 4; r++)
                #pragma unroll
                for (int c = 0; c < 4; c++)
                    acc[r][c] = fmaf(ar[r], br[c], acc[r][c]);
        }
    }

    #pragma unroll
    for (int r = 0; r < 4; r++) {
        #pragma unroll
        for (int c = 0; c < 4; c++) {
            const int i = bm + ty * 4 + r;
            const int n = bn + tx * 4 + c;
            float val = acc[r][c];
            if (OMODE == 0) {
                val += isbf ? us2f(((const unsigned short*)bias)[n]) : ((const float*)bias)[n];
                const int sec = n >> 10, w_ = n & 1023;
                const int h_ = w_ >> 6, d_ = w_ & 63;
                const size_t base = (((size_t)((i >> 9) * HH + h_) * TT + (i & 511)) << 6) + d_;
                if (sec == 0) qT[base] = val;
                else if (sec == 1) kB[base] = f2us(val);
                else vB[base] = f2us(val);
            } else if (OMODE == 1) {
                if (i < M) {
                    const int h_ = n >> 6, d_ = n & 63;
                    pB[(((size_t)h_ * SS + i) << 6) + d_] = f2us(val);
                }
            } else {
                val += isbf ? us2f(((const unsigned short*)bias)[n]) : ((const float*)bias)[n];
                if (isbf) ((unsigned short*)oout)[(size_t)i * N + n] = f2us(val);
                else ((float*)oout)[(size_t)i * N + n] = val;
            }
        }
    }
}

// One wave per (b,h,t): scores -> softmax -> weights (to d_out) + ctx (into qT slot)
__global__ __launch_bounds__(64) void attn_kernel(
    float* __restrict__ qT, const unsigned short* __restrict__ kB,
    const unsigned short* __restrict__ vB, const unsigned short* __restrict__ pB,
    const void* __restrict__ posu, const void* __restrict__ posv,
    const void* __restrict__ mask, void* __restrict__ d_out,
    const int* __restrict__ flags)
{
    const int t = blockIdx.x, h = blockIdx.y, b = blockIdx.z;
    const int lane = threadIdx.x;
    const bool isbf = (flags[0] != 0);
    const bool m32 = (flags[1] != 0);
    __shared__ float qu[64], qv[64], wl[512];

    const size_t bh = (size_t)(b * HH + h);
    const float qval = qT[((bh * TT + t) << 6) + lane];
    const float pu = isbf ? us2f(((const unsigned short*)posu)[h * 64 + lane])
                          : ((const float*)posu)[h * 64 + lane];
    const float pv = isbf ? us2f(((const unsigned short*)posv)[h * 64 + lane])
                          : ((const float*)posv)[h * 64 + lane];
    qu[lane] = qval + pu;
    qv[lane] = qval + pv;
    __syncthreads();

    const ushort4* kp0 = (const ushort4*)(kB + ((bh * TT) << 6));
    const ushort4* pp0 = (const ushort4*)(pB + (((size_t)h * SS) << 6));
    const size_t mbase = ((size_t)(b * TT + t)) * TT;

    float sc[8];
    #pragma unroll
    for (int i = 0; i < 8; i++) {
        const int s = i * 64 + lane;
        const ushort4* kp = kp0 + (size_t)s * 16;
        const ushort4* pp = pp0 + (size_t)(s - t + (TT - 1)) * 16;
        float accA = 0.0f, accB = 0.0f;
        #pragma unroll
        for (int c = 0; c < 16; c++) {
            ushort4 kq = kp[c];
            ushort4 pq = pp[c];
            const int d0 = c * 4;
            accA = fmaf(qu[d0 + 0], us2f(kq.x), accA);
            accA = fmaf(qu[d0 + 1], us2f(kq.y), accA);
            accA = fmaf(qu[d0 + 2], us2f(kq.z), accA);
            accA = fmaf(qu[d0 + 3], us2f(kq.w), accA);
            accB = fmaf(qv[d0 + 0], us2f(pq.x), accB);
            accB = fmaf(qv[d0 + 1], us2f(pq.y), accB);
            accB = fmaf(qv[d0 + 2], us2f(pq.z), accB);
            accB = fmaf(qv[d0 + 3], us2f(pq.w), accB);
        }
        float v = (accA + accB) * 0.125f;
        int mv = m32 ? ((const int*)mask)[mbase + s]
                     : (int)((const signed char*)mask)[mbase + s];
        if (mv == 0) v = -100000.0f;
        sc[i] = v;
    }

    float m = sc[0];
    #pragma unroll
    for (int i = 1; i < 8; i++) m = fmaxf(m, sc[i]);
    #pragma unroll
    for (int off = 32; off; off >>= 1) m = fmaxf(m, __shfl_xor(m, off, 64));

    float e[8];
    float sum = 0.0f;
    #pragma unroll
    for (int i = 0; i < 8; i++) { e[i] = __expf(sc[i] - m); sum += e[i]; }
    #pragma unroll
    for (int off = 32; off; off >>= 1) sum += __shfl_xor(sum, off, 64);
    const float inv = 1.0f / sum;

    const size_t wbase = (size_t)BB * TT * DD + ((bh * TT + t) << 9);
    #pragma unroll
    for (int i = 0; i < 8; i++) {
        const float w = e[i] * inv;
        wl[i * 64 + lane] = w;
        if (isbf) ((unsigned short*)d_out)[wbase + i * 64 + lane] = f2us(w);
        else ((float*)d_out)[wbase + i * 64 + lane] = w;
    }
    __syncthreads();

    const unsigned short* vb = vB + ((bh * TT) << 6) + lane;
    float acc = 0.0f;
    for (int s = 0; s < 512; s++)
        acc = fmaf(wl[s], us2f(vb[(size_t)s << 6]), acc);
    // ctx overwrites this block's own q slot (only this block reads it)
    qT[((bh * TT + t) << 6) + lane] = acc;
}

extern "C" void kernel_launch(void* const* d_in, const int* in_sizes, int n_in,
                              void* d_out, int out_size, void* d_ws, size_t ws_size,
                              hipStream_t stream)
{
    const void* x    = d_in[0];
    const void* mask = d_in[1];
    const void* pos  = d_in[2];
    const void* Wqkv = d_in[3];
    const void* bqkv = d_in[4];
    const void* Wpos = d_in[5];
    const void* posu = d_in[6];
    const void* posv = d_in[7];
    const void* Wout = d_in[8];
    const void* bout = d_in[9];

    char* ws = (char*)d_ws;
    float*          qT    = (float*)(ws + 0);                 // [B,H,T,64] f32 16 MiB (ctx reuses)
    unsigned short* kB    = (unsigned short*)(ws + 16777216); // [B,H,T,64] bf16 8 MiB
    unsigned short* vB    = (unsigned short*)(ws + 25165824); // 8 MiB
    unsigned short* pB    = (unsigned short*)(ws + 33554432); // [H,S,64] bf16 ~2 MiB
    int*            flags = (int*)(ws + 35649536);

    detect_kernel<<<1, 64, 0, stream>>>((const unsigned short*)Wqkv,
                                        (const unsigned int*)mask, flags);

    // 1) qkv = x @ Wqkv^T + bqkv -> q(f32), k/v(bf16) head-major ws
    gemm_kernel<0, 0><<<dim3(48, 64), 256, 0, stream>>>(
        x, Wqkv, bqkv, flags, qT, kB, vB, pB, nullptr, BB * TT, 3 * DD, DD);

    // 2) p = pos @ Wpos^T -> bf16 [H,S,64] ws
    gemm_kernel<0, 1><<<dim3(16, 16), 256, 0, stream>>>(
        pos, Wpos, nullptr, flags, qT, kB, vB, pB, nullptr, SS, DD, DD);

    // 3) attention: weights -> d_out (offset B*T*D), ctx -> qT slots
    attn_kernel<<<dim3(TT, HH, BB), 64, 0, stream>>>(
        qT, kB, vB, pB, posu, posv, mask, d_out, flags);

    // 4) out = ctx @ Wout^T + bout -> d_out[0 .. B*T*D)
    gemm_kernel<2, 2><<<dim3(16, 64), 256, 0, stream>>>(
        nullptr, Wout, bout, flags, qT, kB, vB, pB, d_out, BB * TT, DD, DD);
}

// Round 3
// 1467.427 us; speedup vs baseline: 8.4674x; 8.4674x over previous
//
#include <hip/hip_runtime.h>

#define BB 8
#define TT 512
#define DD 1024
#define HH 16
#define DKK 64
#define SS 1023

__device__ __forceinline__ float us2f(unsigned short u) {
    unsigned int x = ((unsigned int)u) << 16;
    return __uint_as_float(x);
}
__device__ __forceinline__ unsigned short f2us(float f) {
    unsigned int x = __float_as_uint(f);
    unsigned int lsb = (x >> 16) & 1u;
    x += 0x7fffu + lsb;
    return (unsigned short)(x >> 16);
}

// flags[0] = 1 if float buffers are bf16, 0 if f32
// flags[1] = 1 if mask is int32, 0 if int8/bool
__global__ void detect_kernel(const unsigned short* __restrict__ w,
                              const unsigned int* __restrict__ mask,
                              int* __restrict__ flags) {
    if (threadIdx.x == 0 && blockIdx.x == 0) {
        int plaus = 0;
        for (int i = 0; i < 256; i++) {
            unsigned short hw = w[i];
            int e = (hw >> 7) & 0xFF;
            if (e == 0 || (e >= 87 && e <= 131)) plaus++;
        }
        flags[0] = (plaus >= 205) ? 1 : 0;
        int ok = 1;
        for (int i = 0; i < 64; i++) if (mask[i] > 1u) ok = 0;
        flags[1] = ok;
    }
}

// C[i,n] = sum_k A[i,k] * W[n,k] (+ bias[n])
// AMODE: 0 = A external (dtype per flag), 2 = A is ctx f32 in head-major ws layout
// OMODE: 0 = qkv scatter (q->f32 [bh][t][d], k->bf16 TRANSPOSED [bh][d][t], v->bf16 [bh][t][d])
//        1 = pos scatter bf16 TRANSPOSED [h][d][s'] stride 1024
//        2 = output [M,N] (dtype per flag)
template<int AMODE, int OMODE>
__global__ __launch_bounds__(256) void gemm_kernel(
    const void* __restrict__ Av, const void* __restrict__ Wv,
    const void* __restrict__ bias, const int* __restrict__ flags,
    float* __restrict__ qT, unsigned short* __restrict__ kB,
    unsigned short* __restrict__ vB, unsigned short* __restrict__ pB,
    void* __restrict__ oout, int M, int N, int K)
{
    const bool isbf = (flags[0] != 0);
    __shared__ float As[16][64];
    __shared__ float Bs[16][64];
    const int tid = threadIdx.x;
    const int tx = tid & 15, ty = tid >> 4;
    const int bn = blockIdx.x * 64, bm = blockIdx.y * 64;
    const int lm = tid >> 2;          // 0..63
    const int lk = (tid & 3) * 4;     // 0,4,8,12
    float acc[4][4] = {};

    for (int bk = 0; bk < K; bk += 16) {
        float a[4];
        const int gr = bm + lm;
        const bool arow_ok = (OMODE != 1) || (gr < M);
        if (arow_ok) {
            if (AMODE == 0) {
                if (isbf) {
                    const unsigned short* ap = (const unsigned short*)Av + (size_t)gr * K + bk + lk;
                    ushort4 u = *(const ushort4*)ap;
                    a[0] = us2f(u.x); a[1] = us2f(u.y); a[2] = us2f(u.z); a[3] = us2f(u.w);
                } else {
                    const float* ap = (const float*)Av + (size_t)gr * K + bk + lk;
                    float4 u = *(const float4*)ap;
                    a[0] = u.x; a[1] = u.y; a[2] = u.z; a[3] = u.w;
                }
            } else {
                // ctx f32, head-major: A[i][k] = qT[(((i>>9)*16 + (k>>6))*512 + (i&511))*64 + (k&63)]
                const int kk0 = bk + lk;
                const float* ap = qT + (((size_t)(((gr >> 9) * HH) + (kk0 >> 6)) * TT + (gr & 511)) << 6) + (kk0 & 63);
                float4 u = *(const float4*)ap;
                a[0] = u.x; a[1] = u.y; a[2] = u.z; a[3] = u.w;
            }
        } else {
            a[0] = a[1] = a[2] = a[3] = 0.0f;
        }
        float bw[4];
        if (isbf) {
            const unsigned short* wp = (const unsigned short*)Wv + (size_t)(bn + lm) * K + bk + lk;
            ushort4 wu = *(const ushort4*)wp;
            bw[0] = us2f(wu.x); bw[1] = us2f(wu.y); bw[2] = us2f(wu.z); bw[3] = us2f(wu.w);
        } else {
            const float* wp = (const float*)Wv + (size_t)(bn + lm) * K + bk + lk;
            float4 wu = *(const float4*)wp;
            bw[0] = wu.x; bw[1] = wu.y; bw[2] = wu.z; bw[3] = wu.w;
        }

        __syncthreads();
        As[lk + 0][lm] = a[0]; As[lk + 1][lm] = a[1];
        As[lk + 2][lm] = a[2]; As[lk + 3][lm] = a[3];
        Bs[lk + 0][lm] = bw[0]; Bs[lk + 1][lm] = bw[1];
        Bs[lk + 2][lm] = bw[2]; Bs[lk + 3][lm] = bw[3];
        __syncthreads();

        #pragma unroll
        for (int kk = 0; kk < 16; kk++) {
            float4 av = *(const float4*)&As[kk][ty * 4];
            float4 bv = *(const float4*)&Bs[kk][tx * 4];
            float ar[4] = {av.x, av.y, av.z, av.w};
            float br[4] = {bv.x, bv.y, bv.z, bv.w};
            #pragma unroll
            for (int r = 0; r < 4; r++)
                #pragma unroll
                for (int c = 0; c < 4; c++)
                    acc[r][c] = fmaf(ar[r], br[c], acc[r][c]);
        }
    }

    #pragma unroll
    for (int r = 0; r < 4; r++) {
        #pragma unroll
        for (int c = 0; c < 4; c++) {
            const int i = bm + ty * 4 + r;
            const int n = bn + tx * 4 + c;
            float val = acc[r][c];
            if (OMODE == 0) {
                val += isbf ? us2f(((const unsigned short*)bias)[n]) : ((const float*)bias)[n];
                const int sec = n >> 10, w_ = n & 1023;
                const int h_ = w_ >> 6, d_ = w_ & 63;
                const int b_ = i >> 9, t_ = i & 511;
                const size_t bh_ = (size_t)(b_ * HH + h_);
                if (sec == 0) qT[((bh_ * TT + t_) << 6) + d_] = val;
                else if (sec == 1) kB[((bh_ * DKK + d_) << 9) + t_] = f2us(val);  // transposed [bh][d][t]
                else vB[((bh_ * TT + t_) << 6) + d_] = f2us(val);
            } else if (OMODE == 1) {
                if (i < M) {
                    const int h_ = n >> 6, d_ = n & 63;
                    pB[(((size_t)h_ * DKK + d_) << 10) + i] = f2us(val);         // transposed [h][d][s'] stride 1024
                }
            } else {
                val += isbf ? us2f(((const unsigned short*)bias)[n]) : ((const float*)bias)[n];
                if (isbf) ((unsigned short*)oout)[(size_t)i * N + n] = f2us(val);
                else ((float*)oout)[(size_t)i * N + n] = val;
            }
        }
    }
}

// One wave per (b,h,t): scores -> softmax -> weights (to d_out) + ctx (into qT slot)
__global__ __launch_bounds__(64) void attn_kernel(
    float* __restrict__ qT, const unsigned short* __restrict__ kB,
    const unsigned short* __restrict__ vB, const unsigned short* __restrict__ pB,
    const void* __restrict__ posu, const void* __restrict__ posv,
    const void* __restrict__ mask, void* __restrict__ d_out,
    const int* __restrict__ flags)
{
    const int t = blockIdx.x, h = blockIdx.y, b = blockIdx.z;
    const int lane = threadIdx.x;
    const bool isbf = (flags[0] != 0);
    const bool m32 = (flags[1] != 0);
    __shared__ float qu[64], qv[64], wl[512];

    const size_t bh = (size_t)(b * HH + h);
    const float qval = qT[((bh * TT + t) << 6) + lane];
    const float pu = isbf ? us2f(((const unsigned short*)posu)[h * 64 + lane])
                          : ((const float*)posu)[h * 64 + lane];
    const float pv = isbf ? us2f(((const unsigned short*)posv)[h * 64 + lane])
                          : ((const float*)posv)[h * 64 + lane];
    qu[lane] = qval + pu;
    qv[lane] = qval + pv;
    __syncthreads();

    // transposed layouts: kB [bh][d][t] (stride 512), pB [h][d][s'] (stride 1024)
    const unsigned short* kT2 = kB + ((bh * DKK) << 9);
    const unsigned short* pT2 = pB + (((size_t)h * DKK) << 10);
    const size_t mbase = ((size_t)(b * TT + t)) * TT;

    float sc[8];
    #pragma unroll
    for (int i = 0; i < 8; i++) {
        const int s = i * 64 + lane;
        const unsigned short* kc = kT2 + s;                 // coalesced across lanes
        const unsigned short* pc = pT2 + (s - t + (TT - 1)); // coalesced across lanes
        float accA = 0.0f, accB = 0.0f;
        #pragma unroll 16
        for (int d = 0; d < 64; d++) {
            accA = fmaf(qu[d], us2f(kc[d << 9]), accA);
            accB = fmaf(qv[d], us2f(pc[d << 10]), accB);
        }
        float v = (accA + accB) * 0.125f;
        int mv = m32 ? ((const int*)mask)[mbase + s]
                     : (int)((const signed char*)mask)[mbase + s];
        if (mv == 0) v = -100000.0f;
        sc[i] = v;
    }

    float m = sc[0];
    #pragma unroll
    for (int i = 1; i < 8; i++) m = fmaxf(m, sc[i]);
    #pragma unroll
    for (int off = 32; off; off >>= 1) m = fmaxf(m, __shfl_xor(m, off, 64));

    float e[8];
    float sum = 0.0f;
    #pragma unroll
    for (int i = 0; i < 8; i++) { e[i] = __expf(sc[i] - m); sum += e[i]; }
    #pragma unroll
    for (int off = 32; off; off >>= 1) sum += __shfl_xor(sum, off, 64);
    const float inv = 1.0f / sum;

    const size_t wbase = (size_t)BB * TT * DD + ((bh * TT + t) << 9);
    #pragma unroll
    for (int i = 0; i < 8; i++) {
        const float w = e[i] * inv;
        wl[i * 64 + lane] = w;
        if (isbf) ((unsigned short*)d_out)[wbase + i * 64 + lane] = f2us(w);
        else ((float*)d_out)[wbase + i * 64 + lane] = w;
    }
    __syncthreads();

    const unsigned short* vb = vB + ((bh * TT) << 6) + lane;
    float acc = 0.0f;
    for (int s = 0; s < 512; s++)
        acc = fmaf(wl[s], us2f(vb[(size_t)s << 6]), acc);
    // ctx overwrites this block's own q slot (only this block reads it)
    qT[((bh * TT + t) << 6) + lane] = acc;
}

extern "C" void kernel_launch(void* const* d_in, const int* in_sizes, int n_in,
                              void* d_out, int out_size, void* d_ws, size_t ws_size,
                              hipStream_t stream)
{
    const void* x    = d_in[0];
    const void* mask = d_in[1];
    const void* pos  = d_in[2];
    const void* Wqkv = d_in[3];
    const void* bqkv = d_in[4];
    const void* Wpos = d_in[5];
    const void* posu = d_in[6];
    const void* posv = d_in[7];
    const void* Wout = d_in[8];
    const void* bout = d_in[9];

    char* ws = (char*)d_ws;
    float*          qT    = (float*)(ws + 0);                 // [B,H,T,64] f32 16 MiB (ctx reuses)
    unsigned short* kB    = (unsigned short*)(ws + 16777216); // [B,H,64,T] bf16 8 MiB (transposed)
    unsigned short* vB    = (unsigned short*)(ws + 25165824); // [B,H,T,64] bf16 8 MiB
    unsigned short* pB    = (unsigned short*)(ws + 33554432); // [H,64,1024] bf16 2 MiB (transposed)
    int*            flags = (int*)(ws + 36700160);

    detect_kernel<<<1, 64, 0, stream>>>((const unsigned short*)Wqkv,
                                        (const unsigned int*)mask, flags);

    // 1) qkv = x @ Wqkv^T + bqkv -> q(f32), k(bf16 transposed), v(bf16) head-major ws
    gemm_kernel<0, 0><<<dim3(48, 64), 256, 0, stream>>>(
        x, Wqkv, bqkv, flags, qT, kB, vB, pB, nullptr, BB * TT, 3 * DD, DD);

    // 2) p = pos @ Wpos^T -> bf16 transposed [H,64,1024] ws
    gemm_kernel<0, 1><<<dim3(16, 16), 256, 0, stream>>>(
        pos, Wpos, nullptr, flags, qT, kB, vB, pB, nullptr, SS, DD, DD);

    // 3) attention: weights -> d_out (offset B*T*D), ctx -> qT slots
    attn_kernel<<<dim3(TT, HH, BB), 64, 0, stream>>>(
        qT, kB, vB, pB, posu, posv, mask, d_out, flags);

    // 4) out = ctx @ Wout^T + bout -> d_out[0 .. B*T*D)
    gemm_kernel<2, 2><<<dim3(16, 64), 256, 0, stream>>>(
        nullptr, Wout, bout, flags, qT, kB, vB, pB, d_out, BB * TT, DD, DD);
}

// Round 4
// 892.697 us; speedup vs baseline: 13.9188x; 1.6438x over previous
//
#include <hip/hip_runtime.h>

#define BB 8
#define TT 512
#define DD 1024
#define HH 16
#define DKK 64
#define SS 1023

typedef unsigned short u16;
typedef __attribute__((ext_vector_type(8))) short bf16x8;
typedef __attribute__((ext_vector_type(4))) float f32x4;

#define MFMA16(a, b, c) __builtin_amdgcn_mfma_f32_16x16x32_bf16((a), (b), (c), 0, 0, 0)

__device__ __forceinline__ float us2f(u16 u) {
    unsigned int x = ((unsigned int)u) << 16;
    return __uint_as_float(x);
}
__device__ __forceinline__ u16 f2us(float f) {
    unsigned int x = __float_as_uint(f);
    unsigned int lsb = (x >> 16) & 1u;
    x += 0x7fffu + lsb;
    return (u16)(x >> 16);
}

// flags[0] = 1 if float buffers are bf16, 0 if f32
// flags[1] = 1 if mask is int32, 0 if int8/bool
__global__ void detect_kernel(const u16* __restrict__ w,
                              const unsigned int* __restrict__ mask,
                              int* __restrict__ flags) {
    if (threadIdx.x == 0 && blockIdx.x == 0) {
        int plaus = 0;
        for (int i = 0; i < 256; i++) {
            u16 hw = w[i];
            int e = (hw >> 7) & 0xFF;
            if (e == 0 || (e >= 87 && e <= 131)) plaus++;
        }
        flags[0] = (plaus >= 205) ? 1 : 0;
        int ok = 1;
        for (int i = 0; i < 64; i++) if (mask[i] > 1u) ok = 0;
        flags[1] = ok;
    }
}

// ---------------- MFMA GEMM (bf16 path): C[i,n] = sum_k A[i,k]*W[n,k] (+bias)
// OMODE 0: qkv scatter (q->f32 [bh][t][d], k->bf16 [bh][t][d], v->bf16 TRANSPOSED [bh][d][t])
// OMODE 1: pos scatter bf16 [h][s'][d], h-stride 1024 rows, guard i<M
// OMODE 2: A from ctx f32 (qT head-major), out bf16 [M,N] + bias
template<int OMODE>
__global__ __launch_bounds__(256) void gemm_mfma(
    const void* __restrict__ Av, const u16* __restrict__ Wv,
    const void* __restrict__ bias, const int* __restrict__ flags,
    float* __restrict__ qT, u16* __restrict__ kB, u16* __restrict__ vB,
    u16* __restrict__ pB, void* __restrict__ oout, int M, int N, int K)
{
    if (flags[0] == 0) return;  // f32 data handled by vector kernel
    const int tid = threadIdx.x;
    const int w = tid >> 6, lane = tid & 63;
    const int quad = lane >> 4, l16 = lane & 15;
    const int bn = blockIdx.x * 64, bm = blockIdx.y * 64;
    const int arow = min(bm + w * 16 + l16, M - 1);

    f32x4 C[4];
    #pragma unroll
    for (int i = 0; i < 4; i++) { C[i][0] = 0.f; C[i][1] = 0.f; C[i][2] = 0.f; C[i][3] = 0.f; }

    for (int k0 = 0; k0 < K; k0 += 32) {
        bf16x8 a;
        if (OMODE == 2) {
            const int kk = k0 + quad * 8;
            const float* ap = qT + (((size_t)((arow >> 9) * HH + (kk >> 6)) * TT + (arow & 511)) << 6) + (kk & 63);
            float4 f1 = *(const float4*)ap;
            float4 f2 = *(const float4*)(ap + 4);
            a[0] = (short)f2us(f1.x); a[1] = (short)f2us(f1.y);
            a[2] = (short)f2us(f1.z); a[3] = (short)f2us(f1.w);
            a[4] = (short)f2us(f2.x); a[5] = (short)f2us(f2.y);
            a[6] = (short)f2us(f2.z); a[7] = (short)f2us(f2.w);
        } else {
            const u16* ap = (const u16*)Av + (size_t)arow * K + k0 + quad * 8;
            a = *(const bf16x8*)ap;
        }
        #pragma unroll
        for (int ct = 0; ct < 4; ct++) {
            const u16* bp = Wv + (size_t)(bn + ct * 16 + l16) * K + k0 + quad * 8;
            bf16x8 bf = *(const bf16x8*)bp;
            C[ct] = MFMA16(a, bf, C[ct]);
        }
    }

    #pragma unroll
    for (int ct = 0; ct < 4; ct++) {
        #pragma unroll
        for (int r = 0; r < 4; r++) {
            const int i = bm + w * 16 + quad * 4 + r;
            const int n = bn + ct * 16 + l16;
            float val = C[ct][r];
            if (OMODE == 0) {
                val += us2f(((const u16*)bias)[n]);
                const int sec = n >> 10, w_ = n & 1023;
                const int h_ = w_ >> 6, d_ = w_ & 63;
                const size_t bh_ = (size_t)((i >> 9) * HH + h_);
                const int t_ = i & 511;
                if (sec == 0) qT[((bh_ * TT + t_) << 6) + d_] = val;
                else if (sec == 1) kB[((bh_ * TT + t_) << 6) + d_] = f2us(val);
                else vB[((bh_ * DKK + d_) << 9) + t_] = f2us(val);
            } else if (OMODE == 1) {
                if (i < M) {
                    const int h_ = n >> 6, d_ = n & 63;
                    pB[((size_t)(h_ * 1024 + i) << 6) + d_] = f2us(val);
                }
            } else {
                val += us2f(((const u16*)bias)[n]);
                ((u16*)oout)[(size_t)i * N + n] = f2us(val);
            }
        }
    }
}

// ---------------- Vector GEMM (f32 fallback path), early-exits when bf16
template<int AMODE, int OMODE>
__global__ __launch_bounds__(256) void gemm_vec(
    const void* __restrict__ Av, const void* __restrict__ Wv,
    const void* __restrict__ bias, const int* __restrict__ flags,
    float* __restrict__ qT, u16* __restrict__ kB, u16* __restrict__ vB,
    u16* __restrict__ pB, void* __restrict__ oout, int M, int N, int K)
{
    if (flags[0] != 0) return;  // bf16 data handled by MFMA kernel
    __shared__ float As[16][64];
    __shared__ float Bs[16][64];
    const int tid = threadIdx.x;
    const int tx = tid & 15, ty = tid >> 4;
    const int bn = blockIdx.x * 64, bm = blockIdx.y * 64;
    const int lm = tid >> 2;
    const int lk = (tid & 3) * 4;
    float acc[4][4] = {};

    for (int bk = 0; bk < K; bk += 16) {
        float a[4];
        const int gr = bm + lm;
        const bool arow_ok = (OMODE != 1) || (gr < M);
        if (arow_ok) {
            if (AMODE == 0) {
                const float* ap = (const float*)Av + (size_t)gr * K + bk + lk;
                float4 u = *(const float4*)ap;
                a[0] = u.x; a[1] = u.y; a[2] = u.z; a[3] = u.w;
            } else {
                const int kk0 = bk + lk;
                const float* ap = qT + (((size_t)(((gr >> 9) * HH) + (kk0 >> 6)) * TT + (gr & 511)) << 6) + (kk0 & 63);
                float4 u = *(const float4*)ap;
                a[0] = u.x; a[1] = u.y; a[2] = u.z; a[3] = u.w;
            }
        } else {
            a[0] = a[1] = a[2] = a[3] = 0.0f;
        }
        const float* wp = (const float*)Wv + (size_t)(bn + lm) * K + bk + lk;
        float4 wu = *(const float4*)wp;

        __syncthreads();
        As[lk + 0][lm] = a[0]; As[lk + 1][lm] = a[1];
        As[lk + 2][lm] = a[2]; As[lk + 3][lm] = a[3];
        Bs[lk + 0][lm] = wu.x; Bs[lk + 1][lm] = wu.y;
        Bs[lk + 2][lm] = wu.z; Bs[lk + 3][lm] = wu.w;
        __syncthreads();

        #pragma unroll
        for (int kk = 0; kk < 16; kk++) {
            float4 av = *(const float4*)&As[kk][ty * 4];
            float4 bv = *(const float4*)&Bs[kk][tx * 4];
            float ar[4] = {av.x, av.y, av.z, av.w};
            float br[4] = {bv.x, bv.y, bv.z, bv.w};
            #pragma unroll
            for (int r = 0; r < 4; r++)
                #pragma unroll
                for (int c = 0; c < 4; c++)
                    acc[r][c] = fmaf(ar[r], br[c], acc[r][c]);
        }
    }

    #pragma unroll
    for (int r = 0; r < 4; r++) {
        #pragma unroll
        for (int c = 0; c < 4; c++) {
            const int i = bm + ty * 4 + r;
            const int n = bn + tx * 4 + c;
            float val = acc[r][c];
            if (OMODE == 0) {
                val += ((const float*)bias)[n];
                const int sec = n >> 10, w_ = n & 1023;
                const int h_ = w_ >> 6, d_ = w_ & 63;
                const size_t bh_ = (size_t)((i >> 9) * HH + h_);
                const int t_ = i & 511;
                if (sec == 0) qT[((bh_ * TT + t_) << 6) + d_] = val;
                else if (sec == 1) kB[((bh_ * TT + t_) << 6) + d_] = f2us(val);
                else vB[((bh_ * DKK + d_) << 9) + t_] = f2us(val);
            } else if (OMODE == 1) {
                if (i < M) {
                    const int h_ = n >> 6, d_ = n & 63;
                    pB[((size_t)(h_ * 1024 + i) << 6) + d_] = f2us(val);
                }
            } else {
                val += ((const float*)bias)[n];
                ((float*)oout)[(size_t)i * N + n] = val;
            }
        }
    }
}

// ---------------- MFMA attention: block = (t-tile 64, h, b), 4 waves x 16 rows
__global__ __launch_bounds__(256) void attn_mfma(
    float* __restrict__ qT, const u16* __restrict__ kB, const u16* __restrict__ vB,
    const u16* __restrict__ pB, const void* __restrict__ posu,
    const void* __restrict__ posv, const void* __restrict__ mask,
    void* __restrict__ d_out, const int* __restrict__ flags)
{
    const int t0 = blockIdx.x << 6;
    const int h = blockIdx.y, b = blockIdx.z;
    const int tid = threadIdx.x;
    const int w = tid >> 6, lane = tid & 63;
    const int quad = lane >> 4, l16 = lane & 15;
    const bool isbf = (flags[0] != 0), m32 = (flags[1] != 0);
    const size_t bh = (size_t)b * HH + h;

    __shared__ u16 wls[4][16][520];          // per-wave weights tile (also aliased as bd f32)
    u16* wme = &wls[w][0][0];
    float* bdw = (float*)wme;                // [16][84] f32 scratch, per-wave

    // ---- A fragments q_u, q_v (prescaled by 0.125 so scores come out /8)
    const int myrow = t0 + w * 16 + l16;
    const float* qrow = qT + ((bh * TT + myrow) << 6);
    bf16x8 aU[2], aV[2];
    #pragma unroll
    for (int f = 0; f < 2; f++) {
        const int d0 = f * 32 + quad * 8;
        float q8[8], pu8[8], pv8[8];
        *(float4*)&q8[0] = *(const float4*)(qrow + d0);
        *(float4*)&q8[4] = *(const float4*)(qrow + d0 + 4);
        if (isbf) {
            const u16* puP = (const u16*)posu + h * 64 + d0;
            const u16* pvP = (const u16*)posv + h * 64 + d0;
            #pragma unroll
            for (int j = 0; j < 8; j++) { pu8[j] = us2f(puP[j]); pv8[j] = us2f(pvP[j]); }
        } else {
            const float* puP = (const float*)posu + h * 64 + d0;
            const float* pvP = (const float*)posv + h * 64 + d0;
            #pragma unroll
            for (int j = 0; j < 8; j++) { pu8[j] = puP[j]; pv8[j] = pvP[j]; }
        }
        #pragma unroll
        for (int j = 0; j < 8; j++) {
            aU[f][j] = (short)f2us((q8[j] + pu8[j]) * 0.125f);
            aV[f][j] = (short)f2us((q8[j] + pv8[j]) * 0.125f);
        }
    }

    // ---- AC scores: S[32] covers 512 cols (s)
    f32x4 S[32];
    #pragma unroll
    for (int ct = 0; ct < 32; ct++) { S[ct][0] = 0.f; S[ct][1] = 0.f; S[ct][2] = 0.f; S[ct][3] = 0.f; }
    const u16* kbase = kB + ((bh * TT) << 6) + quad * 8;
    #pragma unroll
    for (int ct = 0; ct < 32; ct++) {
        const u16* kp = kbase + ((size_t)(ct * 16 + l16) << 6);
        bf16x8 b0 = *(const bf16x8*)kp;
        bf16x8 b1 = *(const bf16x8*)(kp + 32);
        S[ct] = MFMA16(aU[0], b0, S[ct]);
        S[ct] = MFMA16(aU[1], b1, S[ct]);
    }

    // ---- BD: 8 chunks of 64 cols; per-wave 16x80 tile via LDS, skewed gather
    const u16* pbaseh = pB + ((size_t)h << 16);  // h stride = 1024 rows * 64
    for (int g = 0; g < 8; g++) {
        const int pb = g * 64 - t0 + 496 - w * 16;  // P row for c_local=0 (>=0, <=944)
        #pragma unroll
        for (int c5 = 0; c5 < 5; c5++) {
            const u16* pp = pbaseh + ((size_t)(pb + c5 * 16 + l16) << 6) + quad * 8;
            bf16x8 b0 = *(const bf16x8*)pp;
            bf16x8 b1 = *(const bf16x8*)(pp + 32);
            f32x4 c; c[0] = 0.f; c[1] = 0.f; c[2] = 0.f; c[3] = 0.f;
            c = MFMA16(aV[0], b0, c);
            c = MFMA16(aV[1], b1, c);
            #pragma unroll
            for (int r = 0; r < 4; r++)
                bdw[(quad * 4 + r) * 84 + c5 * 16 + l16] = c[r];
        }
        __syncthreads();
        #pragma unroll
        for (int f = 0; f < 4; f++) {
            const int sc = f * 16 + l16;
            #pragma unroll
            for (int r = 0; r < 4; r++) {
                const int local = quad * 4 + r;
                // bd[local][sc + 15 - local]
                S[g * 4 + f][r] += bdw[local * 83 + sc + 15];
            }
        }
        __syncthreads();
    }

    // ---- mask
    const int trow = t0 + w * 16 + quad * 4;
    #pragma unroll
    for (int ct = 0; ct < 32; ct++) {
        #pragma unroll
        for (int r = 0; r < 4; r++) {
            const size_t midx = (((size_t)b * TT + trow + r) << 9) + ct * 16 + l16;
            const int mv = m32 ? ((const int*)mask)[midx]
                               : (int)((const signed char*)mask)[midx];
            if (mv == 0) S[ct][r] = -100000.0f;
        }
    }

    // ---- softmax (rows live across 16 lanes of this quad)
    float mx[4] = {-3.0e38f, -3.0e38f, -3.0e38f, -3.0e38f};
    float sm[4] = {0.f, 0.f, 0.f, 0.f};
    #pragma unroll
    for (int ct = 0; ct < 32; ct++)
        #pragma unroll
        for (int r = 0; r < 4; r++) mx[r] = fmaxf(mx[r], S[ct][r]);
    #pragma unroll
    for (int r = 0; r < 4; r++)
        #pragma unroll
        for (int off = 1; off < 16; off <<= 1) mx[r] = fmaxf(mx[r], __shfl_xor(mx[r], off, 64));
    #pragma unroll
    for (int ct = 0; ct < 32; ct++)
        #pragma unroll
        for (int r = 0; r < 4; r++) {
            float e = __expf(S[ct][r] - mx[r]);
            S[ct][r] = e;
            sm[r] += e;
        }
    #pragma unroll
    for (int r = 0; r < 4; r++) {
        #pragma unroll
        for (int off = 1; off < 16; off <<= 1) sm[r] += __shfl_xor(sm[r], off, 64);
        sm[r] = 1.0f / sm[r];
    }

    // ---- weights: LDS (A-operand layout source) + global
    __syncthreads();   // retire bd aliasing before weights overwrite
    const size_t wbase = (size_t)BB * TT * DD + (((bh * TT + trow)) << 9) + l16;
    #pragma unroll
    for (int ct = 0; ct < 32; ct++) {
        #pragma unroll
        for (int r = 0; r < 4; r++) {
            const float wv = S[ct][r] * sm[r];
            const u16 u = f2us(wv);
            wls[w][quad * 4 + r][ct * 16 + l16] = u;
            if (isbf) ((u16*)d_out)[wbase + ((size_t)r << 9) + ct * 16] = u;
            else ((float*)d_out)[wbase + ((size_t)r << 9) + ct * 16] = wv;
        }
    }
    __syncthreads();

    // ---- PV: ctx[16x64] = W[16x512] x V[512x64], V transposed [bh][d][s]
    f32x4 Cv[4];
    #pragma unroll
    for (int i = 0; i < 4; i++) { Cv[i][0] = 0.f; Cv[i][1] = 0.f; Cv[i][2] = 0.f; Cv[i][3] = 0.f; }
    const u16* vb0 = vB + ((bh * DKK) << 9) + quad * 8;
    #pragma unroll
    for (int ks = 0; ks < 16; ks++) {
        bf16x8 aw = *(const bf16x8*)&wls[w][l16][ks * 32 + quad * 8];
        #pragma unroll
        for (int ctd = 0; ctd < 4; ctd++) {
            const u16* vp = vb0 + ((size_t)(ctd * 16 + l16) << 9) + ks * 32;
            bf16x8 bv = *(const bf16x8*)vp;
            Cv[ctd] = MFMA16(aw, bv, Cv[ctd]);
        }
    }
    // ctx overwrites this block's own q rows (read-complete)
    float* crow = qT + ((bh * TT + trow) << 6) + l16;
    #pragma unroll
    for (int ctd = 0; ctd < 4; ctd++)
        #pragma unroll
        for (int r = 0; r < 4; r++)
            crow[(r << 6) + ctd * 16] = Cv[ctd][r];
}

extern "C" void kernel_launch(void* const* d_in, const int* in_sizes, int n_in,
                              void* d_out, int out_size, void* d_ws, size_t ws_size,
                              hipStream_t stream)
{
    const void* x    = d_in[0];
    const void* mask = d_in[1];
    const void* pos  = d_in[2];
    const void* Wqkv = d_in[3];
    const void* bqkv = d_in[4];
    const void* Wpos = d_in[5];
    const void* posu = d_in[6];
    const void* posv = d_in[7];
    const void* Wout = d_in[8];
    const void* bout = d_in[9];

    char* ws = (char*)d_ws;
    float* qT    = (float*)(ws + 0);                 // [B,H,T,64] f32 16 MiB (ctx reuses)
    u16*   kB    = (u16*)(ws + 16777216);            // [B,H,T,64] bf16 8 MiB
    u16*   vB    = (u16*)(ws + 25165824);            // [B,H,64,T] bf16 8 MiB (transposed)
    u16*   pB    = (u16*)(ws + 33554432);            // [H,1024,64] bf16 2 MiB (row 1023 = pad)
    int*   flags = (int*)(ws + 35651584);

    detect_kernel<<<1, 64, 0, stream>>>((const u16*)Wqkv, (const unsigned int*)mask, flags);

    // 1) qkv = x @ Wqkv^T + bqkv -> q(f32), k(bf16), v(bf16 transposed)
    gemm_mfma<0><<<dim3(48, 64), 256, 0, stream>>>(
        x, (const u16*)Wqkv, bqkv, flags, qT, kB, vB, pB, nullptr, BB * TT, 3 * DD, DD);
    gemm_vec<0, 0><<<dim3(48, 64), 256, 0, stream>>>(
        x, Wqkv, bqkv, flags, qT, kB, vB, pB, nullptr, BB * TT, 3 * DD, DD);

    // 2) p = pos @ Wpos^T -> bf16 [H,1024,64]
    gemm_mfma<1><<<dim3(16, 16), 256, 0, stream>>>(
        pos, (const u16*)Wpos, nullptr, flags, qT, kB, vB, pB, nullptr, SS, DD, DD);
    gemm_vec<0, 1><<<dim3(16, 16), 256, 0, stream>>>(
        pos, Wpos, nullptr, flags, qT, kB, vB, pB, nullptr, SS, DD, DD);

    // 3) attention: weights -> d_out + B*T*D, ctx -> qT
    attn_mfma<<<dim3(8, HH, BB), 256, 0, stream>>>(
        qT, kB, vB, pB, posu, posv, mask, d_out, flags);

    // 4) out = ctx @ Wout^T + bout
    gemm_mfma<2><<<dim3(16, 64), 256, 0, stream>>>(
        nullptr, (const u16*)Wout, bout, flags, qT, kB, vB, pB, d_out, BB * TT, DD, DD);
    gemm_vec<2, 2><<<dim3(16, 64), 256, 0, stream>>>(
        nullptr, Wout, bout, flags, qT, kB, vB, pB, d_out, BB * TT, DD, DD);
}

// Round 5
// 526.560 us; speedup vs baseline: 23.5971x; 1.6953x over previous
//
#include <hip/hip_runtime.h>

#define BB 8
#define TT 512
#define DD 1024
#define HH 16
#define DKK 64
#define SS 1023

typedef unsigned short u16;
typedef __attribute__((ext_vector_type(8))) short bf16x8;
typedef __attribute__((ext_vector_type(4))) float f32x4;

#define MFMA16(a, b, c) __builtin_amdgcn_mfma_f32_16x16x32_bf16((a), (b), (c), 0, 0, 0)

__device__ __forceinline__ float us2f(u16 u) {
    unsigned int x = ((unsigned int)u) << 16;
    return __uint_as_float(x);
}
__device__ __forceinline__ u16 f2us(float f) {
    unsigned int x = __float_as_uint(f);
    unsigned int lsb = (x >> 16) & 1u;
    x += 0x7fffu + lsb;
    return (u16)(x >> 16);
}
__device__ __forceinline__ bf16x8 cvt8(const float* p) {
    float4 f1 = *(const float4*)p;
    float4 f2 = *(const float4*)(p + 4);
    bf16x8 r;
    r[0] = (short)f2us(f1.x); r[1] = (short)f2us(f1.y);
    r[2] = (short)f2us(f1.z); r[3] = (short)f2us(f1.w);
    r[4] = (short)f2us(f2.x); r[5] = (short)f2us(f2.y);
    r[6] = (short)f2us(f2.z); r[7] = (short)f2us(f2.w);
    return r;
}

// flags[0] = 1 if float buffers are bf16, 0 if f32
// flags[1] = 1 if mask is int32, 0 if int8/bool
__global__ void detect_kernel(const u16* __restrict__ w,
                              const unsigned int* __restrict__ mask,
                              int* __restrict__ flags) {
    if (threadIdx.x == 0 && blockIdx.x == 0) {
        int plaus = 0;
        for (int i = 0; i < 256; i++) {
            u16 hw = w[i];
            int e = (hw >> 7) & 0xFF;
            if (e == 0 || (e >= 87 && e <= 131)) plaus++;
        }
        flags[0] = (plaus >= 205) ? 1 : 0;
        int ok = 1;
        for (int i = 0; i < 64; i++) if (mask[i] > 1u) ok = 0;
        flags[1] = ok;
    }
}

// ---------------- Unified MFMA GEMM: C[i,n] = sum_k A[i,k]*W[n,k] (+bias)
// Handles bf16 AND f32 sources (runtime flag; f32 converted to bf16 during LDS staging).
// OMODE 0: qkv scatter (q->f32 [bh][t][d], k->bf16 [bh][t][d], v->bf16 TRANSPOSED [bh][d][t])
// OMODE 1: pos scatter bf16 [h][s'][d], h-stride 1024 rows, guard i<M
// OMODE 2: A from ctx f32 (qT head-major), out [M,N] + bias (dtype per flag)
template<int OMODE>
__global__ __launch_bounds__(256) void gemm_mfma(
    const void* __restrict__ Av, const void* __restrict__ Wv,
    const void* __restrict__ bias, const int* __restrict__ flags,
    float* __restrict__ qT, u16* __restrict__ kB, u16* __restrict__ vB,
    u16* __restrict__ pB, void* __restrict__ oout, int M, int N, int K)
{
    const bool isbf = (flags[0] != 0);
    __shared__ u16 As[64][40];   // [m 0..63][k 0..31], +8 pad
    __shared__ u16 Bs[64][40];   // [n 0..63][k 0..31], +8 pad
    const int tid = threadIdx.x;
    const int w = tid >> 6, lane = tid & 63;
    const int quad = lane >> 4, l16 = lane & 15;
    const int bn = blockIdx.x * 64, bm = blockIdx.y * 64;
    const int srow = tid >> 2;          // 0..63 staging row
    const int koff = (tid & 3) * 8;     // 0,8,16,24
    const int garow = (OMODE == 1) ? min(bm + srow, M - 1) : (bm + srow);
    const int gbrow = bn + srow;

    f32x4 C[4];
    #pragma unroll
    for (int i = 0; i < 4; i++) { C[i][0] = 0.f; C[i][1] = 0.f; C[i][2] = 0.f; C[i][3] = 0.f; }

    for (int k0 = 0; k0 < K; k0 += 32) {
        bf16x8 av, bv;
        if (OMODE == 2) {
            const int kk = k0 + koff;
            const float* ap = qT + (((size_t)((garow >> 9) * HH + (kk >> 6)) * TT + (garow & 511)) << 6) + (kk & 63);
            av = cvt8(ap);
        } else if (isbf) {
            av = *(const bf16x8*)((const u16*)Av + (size_t)garow * K + k0 + koff);
        } else {
            av = cvt8((const float*)Av + (size_t)garow * K + k0 + koff);
        }
        if (isbf) {
            bv = *(const bf16x8*)((const u16*)Wv + (size_t)gbrow * K + k0 + koff);
        } else {
            bv = cvt8((const float*)Wv + (size_t)gbrow * K + k0 + koff);
        }

        __syncthreads();
        *(bf16x8*)&As[srow][koff] = av;
        *(bf16x8*)&Bs[srow][koff] = bv;
        __syncthreads();

        bf16x8 af = *(const bf16x8*)&As[w * 16 + l16][quad * 8];
        #pragma unroll
        for (int ct = 0; ct < 4; ct++) {
            bf16x8 bf = *(const bf16x8*)&Bs[ct * 16 + l16][quad * 8];
            C[ct] = MFMA16(af, bf, C[ct]);
        }
    }

    #pragma unroll
    for (int ct = 0; ct < 4; ct++) {
        #pragma unroll
        for (int r = 0; r < 4; r++) {
            const int i = bm + w * 16 + quad * 4 + r;
            const int n = bn + ct * 16 + l16;
            float val = C[ct][r];
            if (OMODE == 0) {
                val += isbf ? us2f(((const u16*)bias)[n]) : ((const float*)bias)[n];
                const int sec = n >> 10, w_ = n & 1023;
                const int h_ = w_ >> 6, d_ = w_ & 63;
                const size_t bh_ = (size_t)((i >> 9) * HH + h_);
                const int t_ = i & 511;
                if (sec == 0) qT[((bh_ * TT + t_) << 6) + d_] = val;
                else if (sec == 1) kB[((bh_ * TT + t_) << 6) + d_] = f2us(val);
                else vB[((bh_ * DKK + d_) << 9) + t_] = f2us(val);
            } else if (OMODE == 1) {
                if (i < M) {
                    const int h_ = n >> 6, d_ = n & 63;
                    pB[((size_t)(h_ * 1024 + i) << 6) + d_] = f2us(val);
                }
            } else {
                val += isbf ? us2f(((const u16*)bias)[n]) : ((const float*)bias)[n];
                if (isbf) ((u16*)oout)[(size_t)i * N + n] = f2us(val);
                else ((float*)oout)[(size_t)i * N + n] = val;
            }
        }
    }
}

// ---------------- MFMA attention: block = (t-tile 64, h, b), 4 waves x 16 rows
__global__ __launch_bounds__(256) void attn_mfma(
    float* __restrict__ qT, const u16* __restrict__ kB, const u16* __restrict__ vB,
    const u16* __restrict__ pB, const void* __restrict__ posu,
    const void* __restrict__ posv, const void* __restrict__ mask,
    void* __restrict__ d_out, const int* __restrict__ flags)
{
    const int t0 = blockIdx.x << 6;
    const int h = blockIdx.y, b = blockIdx.z;
    const int tid = threadIdx.x;
    const int w = tid >> 6, lane = tid & 63;
    const int quad = lane >> 4, l16 = lane & 15;
    const bool isbf = (flags[0] != 0), m32 = (flags[1] != 0);
    const size_t bh = (size_t)b * HH + h;

    __shared__ u16 wls[4][16][520];          // per-wave weights tile (also aliased as bd f32)
    u16* wme = &wls[w][0][0];
    float* bdw = (float*)wme;                // [16][84] f32 scratch, per-wave

    // ---- A fragments q_u, q_v (prescaled by 0.125 so scores come out /8)
    const int myrow = t0 + w * 16 + l16;
    const float* qrow = qT + ((bh * TT + myrow) << 6);
    bf16x8 aU[2], aV[2];
    #pragma unroll
    for (int f = 0; f < 2; f++) {
        const int d0 = f * 32 + quad * 8;
        float q8[8], pu8[8], pv8[8];
        *(float4*)&q8[0] = *(const float4*)(qrow + d0);
        *(float4*)&q8[4] = *(const float4*)(qrow + d0 + 4);
        if (isbf) {
            const u16* puP = (const u16*)posu + h * 64 + d0;
            const u16* pvP = (const u16*)posv + h * 64 + d0;
            #pragma unroll
            for (int j = 0; j < 8; j++) { pu8[j] = us2f(puP[j]); pv8[j] = us2f(pvP[j]); }
        } else {
            const float* puP = (const float*)posu + h * 64 + d0;
            const float* pvP = (const float*)posv + h * 64 + d0;
            #pragma unroll
            for (int j = 0; j < 8; j++) { pu8[j] = puP[j]; pv8[j] = pvP[j]; }
        }
        #pragma unroll
        for (int j = 0; j < 8; j++) {
            aU[f][j] = (short)f2us((q8[j] + pu8[j]) * 0.125f);
            aV[f][j] = (short)f2us((q8[j] + pv8[j]) * 0.125f);
        }
    }

    // ---- AC scores: S[32] covers 512 cols (s)
    f32x4 S[32];
    #pragma unroll
    for (int ct = 0; ct < 32; ct++) { S[ct][0] = 0.f; S[ct][1] = 0.f; S[ct][2] = 0.f; S[ct][3] = 0.f; }
    const u16* kbase = kB + ((bh * TT) << 6) + quad * 8;
    #pragma unroll
    for (int ct = 0; ct < 32; ct++) {
        const u16* kp = kbase + ((size_t)(ct * 16 + l16) << 6);
        bf16x8 b0 = *(const bf16x8*)kp;
        bf16x8 b1 = *(const bf16x8*)(kp + 32);
        S[ct] = MFMA16(aU[0], b0, S[ct]);
        S[ct] = MFMA16(aU[1], b1, S[ct]);
    }

    // ---- BD: 8 chunks of 64 cols; per-wave 16x80 tile via LDS, skewed gather
    const u16* pbaseh = pB + ((size_t)h << 16);  // h stride = 1024 rows * 64
    for (int g = 0; g < 8; g++) {
        const int pb = g * 64 - t0 + 496 - w * 16;  // P row for c_local=0 (>=0, <=944)
        #pragma unroll
        for (int c5 = 0; c5 < 5; c5++) {
            const u16* pp = pbaseh + ((size_t)(pb + c5 * 16 + l16) << 6) + quad * 8;
            bf16x8 b0 = *(const bf16x8*)pp;
            bf16x8 b1 = *(const bf16x8*)(pp + 32);
            f32x4 c; c[0] = 0.f; c[1] = 0.f; c[2] = 0.f; c[3] = 0.f;
            c = MFMA16(aV[0], b0, c);
            c = MFMA16(aV[1], b1, c);
            #pragma unroll
            for (int r = 0; r < 4; r++)
                bdw[(quad * 4 + r) * 84 + c5 * 16 + l16] = c[r];
        }
        __syncthreads();
        #pragma unroll
        for (int f = 0; f < 4; f++) {
            const int sc = f * 16 + l16;
            #pragma unroll
            for (int r = 0; r < 4; r++) {
                const int local = quad * 4 + r;
                // bd[local][sc + 15 - local]
                S[g * 4 + f][r] += bdw[local * 83 + sc + 15];
            }
        }
        __syncthreads();
    }

    // ---- mask
    const int trow = t0 + w * 16 + quad * 4;
    #pragma unroll
    for (int ct = 0; ct < 32; ct++) {
        #pragma unroll
        for (int r = 0; r < 4; r++) {
            const size_t midx = (((size_t)b * TT + trow + r) << 9) + ct * 16 + l16;
            const int mv = m32 ? ((const int*)mask)[midx]
                               : (int)((const signed char*)mask)[midx];
            if (mv == 0) S[ct][r] = -100000.0f;
        }
    }

    // ---- softmax (rows live across 16 lanes of this quad)
    float mx[4] = {-3.0e38f, -3.0e38f, -3.0e38f, -3.0e38f};
    float sm[4] = {0.f, 0.f, 0.f, 0.f};
    #pragma unroll
    for (int ct = 0; ct < 32; ct++)
        #pragma unroll
        for (int r = 0; r < 4; r++) mx[r] = fmaxf(mx[r], S[ct][r]);
    #pragma unroll
    for (int r = 0; r < 4; r++)
        #pragma unroll
        for (int off = 1; off < 16; off <<= 1) mx[r] = fmaxf(mx[r], __shfl_xor(mx[r], off, 64));
    #pragma unroll
    for (int ct = 0; ct < 32; ct++)
        #pragma unroll
        for (int r = 0; r < 4; r++) {
            float e = __expf(S[ct][r] - mx[r]);
            S[ct][r] = e;
            sm[r] += e;
        }
    #pragma unroll
    for (int r = 0; r < 4; r++) {
        #pragma unroll
        for (int off = 1; off < 16; off <<= 1) sm[r] += __shfl_xor(sm[r], off, 64);
        sm[r] = 1.0f / sm[r];
    }

    // ---- weights: LDS (A-operand layout source) + global
    __syncthreads();   // retire bd aliasing before weights overwrite
    const size_t wbase = (size_t)BB * TT * DD + (((bh * TT + trow)) << 9) + l16;
    #pragma unroll
    for (int ct = 0; ct < 32; ct++) {
        #pragma unroll
        for (int r = 0; r < 4; r++) {
            const float wv = S[ct][r] * sm[r];
            const u16 u = f2us(wv);
            wls[w][quad * 4 + r][ct * 16 + l16] = u;
            if (isbf) ((u16*)d_out)[wbase + ((size_t)r << 9) + ct * 16] = u;
            else ((float*)d_out)[wbase + ((size_t)r << 9) + ct * 16] = wv;
        }
    }
    __syncthreads();

    // ---- PV: ctx[16x64] = W[16x512] x V[512x64], V transposed [bh][d][s]
    f32x4 Cv[4];
    #pragma unroll
    for (int i = 0; i < 4; i++) { Cv[i][0] = 0.f; Cv[i][1] = 0.f; Cv[i][2] = 0.f; Cv[i][3] = 0.f; }
    const u16* vb0 = vB + ((bh * DKK) << 9) + quad * 8;
    #pragma unroll
    for (int ks = 0; ks < 16; ks++) {
        bf16x8 aw = *(const bf16x8*)&wls[w][l16][ks * 32 + quad * 8];
        #pragma unroll
        for (int ctd = 0; ctd < 4; ctd++) {
            const u16* vp = vb0 + ((size_t)(ctd * 16 + l16) << 9) + ks * 32;
            bf16x8 bv = *(const bf16x8*)vp;
            Cv[ctd] = MFMA16(aw, bv, Cv[ctd]);
        }
    }
    // ctx overwrites this block's own q rows (read-complete)
    float* crow = qT + ((bh * TT + trow) << 6) + l16;
    #pragma unroll
    for (int ctd = 0; ctd < 4; ctd++)
        #pragma unroll
        for (int r = 0; r < 4; r++)
            crow[(r << 6) + ctd * 16] = Cv[ctd][r];
}

extern "C" void kernel_launch(void* const* d_in, const int* in_sizes, int n_in,
                              void* d_out, int out_size, void* d_ws, size_t ws_size,
                              hipStream_t stream)
{
    const void* x    = d_in[0];
    const void* mask = d_in[1];
    const void* pos  = d_in[2];
    const void* Wqkv = d_in[3];
    const void* bqkv = d_in[4];
    const void* Wpos = d_in[5];
    const void* posu = d_in[6];
    const void* posv = d_in[7];
    const void* Wout = d_in[8];
    const void* bout = d_in[9];

    char* ws = (char*)d_ws;
    float* qT    = (float*)(ws + 0);                 // [B,H,T,64] f32 16 MiB (ctx reuses)
    u16*   kB    = (u16*)(ws + 16777216);            // [B,H,T,64] bf16 8 MiB
    u16*   vB    = (u16*)(ws + 25165824);            // [B,H,64,T] bf16 8 MiB (transposed)
    u16*   pB    = (u16*)(ws + 33554432);            // [H,1024,64] bf16 2 MiB (row 1023 = pad)
    int*   flags = (int*)(ws + 35651584);

    detect_kernel<<<1, 64, 0, stream>>>((const u16*)Wqkv, (const unsigned int*)mask, flags);

    // 1) qkv = x @ Wqkv^T + bqkv -> q(f32), k(bf16), v(bf16 transposed)
    gemm_mfma<0><<<dim3(48, 64), 256, 0, stream>>>(
        x, Wqkv, bqkv, flags, qT, kB, vB, pB, nullptr, BB * TT, 3 * DD, DD);

    // 2) p = pos @ Wpos^T -> bf16 [H,1024,64]
    gemm_mfma<1><<<dim3(16, 16), 256, 0, stream>>>(
        pos, Wpos, nullptr, flags, qT, kB, vB, pB, nullptr, SS, DD, DD);

    // 3) attention: weights -> d_out + B*T*D, ctx -> qT
    attn_mfma<<<dim3(8, HH, BB), 256, 0, stream>>>(
        qT, kB, vB, pB, posu, posv, mask, d_out, flags);

    // 4) out = ctx @ Wout^T + bout
    gemm_mfma<2><<<dim3(16, 64), 256, 0, stream>>>(
        nullptr, Wout, bout, flags, qT, kB, vB, pB, d_out, BB * TT, DD, DD);
}